// Round 5
// baseline (243.662 us; speedup 1.0000x reference)
//
#include <hip/hip_runtime.h>
#include <math.h>

// ---------------- problem constants ----------------
#define SRATE   44100
#define T_IN    441000
#define BATCH   8
#define NB      3
#define NSEQ    (NB*BATCH)        // 24
#define TB_OUT  160000
#define NEW_R   160
#define ORIG_R  441
#define KW      475               // sinc kernel taps
#define KWP     476               // padded to /4
#define WIDTH   17
#define NFRAMES 1000

// IIR chunking: 441000 = 2625 * 168 ; warmup 128 (worst pole 0.9359 -> 2.1e-4 residual,
// ~1.3e-3 output effect -- invisible under the bf16 comparison / 0.018 threshold)
#define LCHUNK  168
#define NCHUNK  2625
#define WARM    128

// workspace layout
#define XLP_OFF (1u<<20)          // 1 MB; kt table at offset 0 (304,640 B)

// ---------------- sinc resample kernel table (replicates numpy f64 math) ----------------
__global__ void kt_init_kernel(float* __restrict__ kt) {
    int idx = blockIdx.x * blockDim.x + threadIdx.x;
    if (idx >= KWP * NEW_R) return;
    int j = idx / NEW_R, p = idx % NEW_R;   // layout kt[j][p] (transposed vs ref) for coalesced reads
    float v = 0.f;
    if (j < KW) {
        const double base = 160.0 * 0.99;   // 158.4
        double t = (-(double)p) / 160.0 + ((double)(j - WIDTH)) / 441.0;
        t *= base;
        t = fmin(6.0, fmax(-6.0, t));
        double win = cos(t * M_PI / 6.0 / 2.0); win *= win;
        double tp = t * M_PI;
        double s = (tp == 0.0) ? 1.0 : sin(tp) / tp;
        v = (float)(s * win * (base / 441.0));
    }
    kt[idx] = v;
}

// ---------------- fused bandpass -> clip -> cos mix -> lowpass -> clip scan (all f32) ----
// Heterodyne replicates the XLA-f32 reference arithmetic:
//   tf = fl32( fl32(n) * fl32(1/44100) )   <-- XLA rewrites x/const into x*(1/const)!
//   X  = fl32( w_f32 * tf ),  w_f32 = fl32(fl32(2pi) * c)
// then cos(X) computed accurately (f64 range reduction to revolutions + v_cos_f32),
// which R1==R4 showed is bit-consistent with libm cosf at our accuracy scale.
struct ScanParams {
    float b0[NB], a1[NB], a2[NB], w[NB];
    float lb0, lb1, lb2, la1, la2;
};

__global__ __launch_bounds__(256) void scan_kernel(const float* __restrict__ x,
                                                   float* __restrict__ xlp,
                                                   ScanParams P) {
    int id = blockIdx.x * blockDim.x + threadIdx.x;
    if (id >= NSEQ * NCHUNK) return;
    int seq   = id / NCHUNK;          // consecutive lanes = consecutive chunks of one seq
    int chunk = id - seq * NCHUNK;
    int band  = seq / BATCH;
    int batch = seq - band * BATCH;

    // constant-index selects (keeps kernel args in SGPRs, no scratch)
    float b0f = (band == 0) ? P.b0[0] : (band == 1) ? P.b0[1] : P.b0[2];
    float a1f = (band == 0) ? P.a1[0] : (band == 1) ? P.a1[1] : P.a1[2];
    float a2f = (band == 0) ? P.a2[0] : (band == 1) ? P.a2[1] : P.a2[2];
    float wf  = (band == 0) ? P.w[0]  : (band == 1) ? P.w[1]  : P.w[2];
    float b2f = -b0f;                 // bandpass b2 = -b0
    float lb0 = P.lb0, lb1 = P.lb1, lb2 = P.lb2, la1 = P.la1, la2 = P.la2;

    const float*  xr   = x + batch * T_IN;
    float*        orow = xlp + seq * T_IN;
    const float4* xr4  = (const float4*)xr;

    int t0 = chunk * LCHUNK;          // multiple of 4 -> float4 aligned
    int s0 = t0 - WARM; if (s0 < 0) s0 = 0;
    int e  = t0 + LCHUNK;

    float bx1 = 0.f, bx2 = 0.f, by1 = 0.f, by2 = 0.f;   // bandpass state (UNclipped feedback)
    float mx1 = 0.f, mx2 = 0.f, mz1 = 0.f, mz2 = 0.f;   // lowpass state

    const float  invsr  = 1.0f / 44100.0f;      // fl32(1/44100) -- XLA's folded reciprocal
    const double inv2pi = 0.15915494309189535;  // fl64(1/(2pi))

    float4 xv = xr4[s0 >> 2];
    for (int s = s0; s < e; s += 4) {
        float4 xn;
        if (s + 4 < e) xn = xr4[(s >> 2) + 1];
        else           xn = make_float4(0.f, 0.f, 0.f, 0.f);

        float o0, o1, o2, o3;
#define STEP(XT, TI, OUT) {                                                   \
        float y  = b0f*(XT) + b2f*bx2 - a1f*by1 - a2f*by2;                    \
        bx2 = bx1; bx1 = (XT); by2 = by1; by1 = y;                            \
        float cy = fminf(fmaxf(y, -1.f), 1.f);                                \
        float tf = (float)(TI) * invsr;      /* reciprocal-mul, == XLA */     \
        float X  = wf * tf;                  /* f32 product, == XLA   */      \
        double rv = (double)X * inv2pi;                                       \
        double fr = rv - floor(rv);                                           \
        float cv = __builtin_amdgcn_cosf((float)fr);  /* rev input */         \
        float m  = cy * cv;                                                   \
        float z  = lb0*m + lb1*mx1 + lb2*mx2 - la1*mz1 - la2*mz2;             \
        mx2 = mx1; mx1 = m; mz2 = mz1; mz1 = z;                               \
        OUT = fminf(fmaxf(z, -1.f), 1.f); }

        STEP(xv.x, s,     o0)
        STEP(xv.y, s + 1, o1)
        STEP(xv.z, s + 2, o2)
        STEP(xv.w, s + 3, o3)
#undef STEP
        if (s >= t0) ((float4*)orow)[s >> 2] = make_float4(o0, o1, o2, o3);
        xv = xn;
    }
}

// ---------------- polyphase resample: out[seq,f,p] = sum_j kt[j][p] * xlp[f*441 + j - 17] ----------------
#define FB    32      // frames per block
#define ROWW  480     // padded row (16B-aligned rows, covers j<=478)

__device__ inline void fma4(float4& a, float s, const float4& k) {
    a.x += s * k.x; a.y += s * k.y; a.z += s * k.z; a.w += s * k.w;
}

__global__ __launch_bounds__(160) void resample_kernel(const float* __restrict__ xlp,
                                                       const float* __restrict__ kt,
                                                       float* __restrict__ out) {
    __shared__ float xs[FB * ROWW];   // 61,440 B
    int bid = blockIdx.x;
    int seq = bid >> 5;               // 32 frame-groups per sequence
    int bg  = bid & 31;
    int f0  = bg * FB;
    int band  = seq / BATCH;
    int batch = seq - band * BATCH;
    const float* xr = xlp + seq * T_IN;

    // stage x windows: row f holds xlp[(f0+f)*441 - 17 .. +478), OOB/pad -> 0
    for (int i = threadIdx.x; i < FB * ROWW; i += 160) {
        int f = i / ROWW, c = i - f * ROWW;
        float v = 0.f;
        int src = (f0 + f) * ORIG_R - WIDTH + c;
        if (c < KW && src >= 0 && src < T_IN) v = xr[src];
        xs[i] = v;
    }
    __syncthreads();

    int pg = threadIdx.x % 20;        // 20 phase-groups x 8 phases = 160
    int fg = threadIdx.x / 20;        // 8 frame-groups x 4 frames  = 32
    int p0 = pg * 8;

    float4 acc[4][2];
#pragma unroll
    for (int f = 0; f < 4; ++f) {
        acc[f][0] = make_float4(0.f, 0.f, 0.f, 0.f);
        acc[f][1] = make_float4(0.f, 0.f, 0.f, 0.f);
    }

    for (int jt = 0; jt < KWP / 4; ++jt) {   // 119 tiles of 4 taps
        int j = jt << 2;
        const float* kr = kt + j * NEW_R + p0;
        float4 k0a = *(const float4*)(kr);
        float4 k0b = *(const float4*)(kr + 4);
        float4 k1a = *(const float4*)(kr + NEW_R);
        float4 k1b = *(const float4*)(kr + NEW_R + 4);
        float4 k2a = *(const float4*)(kr + 2 * NEW_R);
        float4 k2b = *(const float4*)(kr + 2 * NEW_R + 4);
        float4 k3a = *(const float4*)(kr + 3 * NEW_R);
        float4 k3b = *(const float4*)(kr + 3 * NEW_R + 4);
#pragma unroll
        for (int f = 0; f < 4; ++f) {
            float4 xv = *(const float4*)(&xs[(fg * 4 + f) * ROWW + j]);  // aligned b128
            fma4(acc[f][0], xv.x, k0a); fma4(acc[f][1], xv.x, k0b);
            fma4(acc[f][0], xv.y, k1a); fma4(acc[f][1], xv.y, k1b);
            fma4(acc[f][0], xv.z, k2a); fma4(acc[f][1], xv.z, k2b);
            fma4(acc[f][0], xv.w, k3a); fma4(acc[f][1], xv.w, k3b);
        }
    }

    int obase = (batch * NB + band) * TB_OUT;   // output is (B, nb, Tb)
#pragma unroll
    for (int f = 0; f < 4; ++f) {
        int fr = f0 + fg * 4 + f;
        if (fr < NFRAMES) {
            float4* o = (float4*)(out + obase + fr * NEW_R + p0);
            o[0] = acc[f][0];
            o[1] = acc[f][1];
        }
    }
}

// ---------------- host ----------------
extern "C" void kernel_launch(void* const* d_in, const int* in_sizes, int n_in,
                              void* d_out, int out_size, void* d_ws, size_t ws_size,
                              hipStream_t stream) {
    const float* x   = (const float*)d_in[0];
    float*       out = (float*)d_out;
    float*       kt  = (float*)d_ws;
    float*       xlp = (float*)((char*)d_ws + XLP_OFF);

    // biquad coefficients computed in f64 on host, cast f32 (bit-matches the reference's
    // math.* -> np.array -> asarray(f32) path)
    ScanParams P;
    const double centers[NB] = {4000.0, 12000.0, 19025.0};
    const double Qs[NB]      = {0.5, 1.5, 19025.0 / 6050.0};
    for (int b = 0; b < NB; ++b) {
        double c  = centers[b], Q = Qs[b];
        double w0 = 2.0 * M_PI * c / 44100.0;
        double al = sin(w0) / (2.0 * Q);
        double a0 = 1.0 + al;
        P.b0[b] = (float)(al / a0);
        P.a1[b] = (float)(-2.0 * cos(w0) / a0);
        P.a2[b] = (float)((1.0 - al) / a0);
        // w = fl32(fl32(2pi) * fl32(c)) -- f32 weak-scalar product, as jax/np compute it
        P.w[b]  = 6.283185307179586f * (float)c;
    }
    {
        double cut = 0.45 * 16000.0;                 // 7200
        double Q   = 0.7071067811865476;
        double w0  = 2.0 * M_PI * cut / 44100.0;
        double al  = sin(w0) / (2.0 * Q);
        double cs  = cos(w0);
        double a0  = 1.0 + al;
        P.lb0 = (float)(((1.0 - cs) / 2.0) / a0);
        P.lb1 = (float)((1.0 - cs) / a0);
        P.lb2 = P.lb0;
        P.la1 = (float)(-2.0 * cs / a0);
        P.la2 = (float)((1.0 - al) / a0);
    }

    // 1) sinc table (476x160 f32, ~305 KB at ws+0)
    kt_init_kernel<<<dim3((KWP * NEW_R + 255) / 256), dim3(256), 0, stream>>>(kt);

    // 2) fused IIR cascade -> xlp (24 x 441000 f32 at ws+1MB), 63000 warm-up chunks
    int nthreads = NSEQ * NCHUNK;                    // 63000
    scan_kernel<<<dim3((nthreads + 255) / 256), dim3(256), 0, stream>>>(x, xlp, P);

    // 3) polyphase resample -> out (8 x 3 x 160000)
    resample_kernel<<<dim3(NSEQ * 32), dim3(160), 0, stream>>>(xlp, kt, out);
}